// Round 7
// baseline (111.208 us; speedup 1.0000x reference)
//
#include <hip/hip_runtime.h>
#include <cstddef>

#define RR 80
#define NVIEW 4
#define CH 32
#define IH 64
#define IW 64
#define NPIX (IH*IW)
#define NVOX (RR*RR*RR)   // 512000

// G (f16) layout: [v][grp(4 x 8ch)][y][x][8 f16 = 16B]
#define PLANE_H (NPIX*8)
#define VIEW_H  (4*PLANE_H)

typedef _Float16 half4_t  __attribute__((ext_vector_type(4)));
typedef _Float16 half8_t  __attribute__((ext_vector_type(8)));
typedef float    float4_t __attribute__((ext_vector_type(4)));

#define H2T_STRIDE 20   // f16; write banks form a full 32-bank permutation

// ---------------------------------------------------------------------------
// G[v][g][y][x][e] = sum_ic feats[v][ic][y][x] * W1[ic][8*g+e]  (f16 output)
// ---------------------------------------------------------------------------
__global__ __launch_bounds__(256) void g_precompute(
    const float* __restrict__ feats, const float* __restrict__ W1,
    _Float16* __restrict__ G)
{
    int g = blockIdx.x >> 6;                        // 0..3 (8-ch group)
    int p = (blockIdx.x & 63)*256 + threadIdx.x;    // pixel 0..16383
    __shared__ float sW1[CH*8];
    if (threadIdx.x < CH*8) {
        int ic = threadIdx.x >> 3, e = threadIdx.x & 7;
        sW1[threadIdx.x] = W1[ic*CH + 8*g + e];
    }
    __syncthreads();
    int v  = p >> 12;
    int yx = p & 4095;
    const float* fb = feats + ((size_t)v*CH)*NPIX + yx;
    float acc[8];
    #pragma unroll
    for (int e=0;e<8;++e) acc[e] = 0.f;
    #pragma unroll
    for (int ic=0; ic<CH; ++ic) {
        float fv = fb[(size_t)ic*NPIX];
        #pragma unroll
        for (int e=0;e<8;++e) acc[e] = fmaf(fv, sW1[ic*8+e], acc[e]);
    }
    half8_t h;
    #pragma unroll
    for (int e=0;e<8;++e) h[e] = (_Float16)acc[e];
    *(half8_t*)(G + (size_t)v*VIEW_H + (size_t)g*PLANE_H + (size_t)yx*8) = h;
}

// ---------------------------------------------------------------------------
// Main: wave = 16(i) x 4(j) voxel tile (L1-line locality for the gathers);
// f16 packed blend; MLP (W2,W3) via MFMA with wave-resident weights.
// Block = 4 waves stacked in j -> 16x16x1 tile. Grid 5 x 5 x 80 = 2000.
// ---------------------------------------------------------------------------
__global__ __launch_bounds__(256) void dgfv_main(
    const _Float16* __restrict__ G,   // [NVIEW][4][IH][IW][8]
    const float* __restrict__ poses,
    const float* __restrict__ b1,
    const float* __restrict__ W2, const float* __restrict__ b2,
    const float* __restrict__ W3, const float* __restrict__ b3,
    float* __restrict__ out)
{
    __shared__ __align__(16) _Float16 h1buf[4][64*40];        // 80 B row stride
    __shared__ __align__(16) float    mkbuf[4][64];
    __shared__ __align__(16) _Float16 h2t[4][16*H2T_STRIDE];  // padded 16x16

    const int wid  = threadIdx.x >> 6;
    const int lane = threadIdx.x & 63;
    const int lq   = lane >> 4;
    const int lc   = lane & 15;
    const int li   = lane & 15;      // i within tile
    const int lj   = lane >> 4;      // j within wave

    // block -> (i-tile, j-tile, k)
    int bi = blockIdx.x % 5;
    int bt = blockIdx.x / 5;
    int bj = bt % 5;
    int k_ = bt / 5;
    int i  = bi*16 + li;
    int j_ = bj*16 + wid*4 + lj;
    const int vox = k_*(RR*RR) + j_*RR + i;   // this lane's global voxel

    // wave-resident weight fragments
    half8_t w2f;                     // B-frag 16x16x32: k = lq*8+j, n = lc
    #pragma unroll
    for (int j=0;j<8;++j) w2f[j] = (_Float16)W2[(lq*8+j)*16 + lc];
    half4_t w3f;                     // B-frag 16x16x16: k = lq*4+j, n = lc (<8)
    #pragma unroll
    for (int j=0;j<4;++j) w3f[j] = (lc<8) ? (_Float16)W3[(lq*4+j)*8 + lc]
                                          : (_Float16)0.f;
    const float b2c = b2[lc];
    const float b3c = (lc<8) ? b3[lc] : 0.f;
    const float4_t c1init = {b2c,b2c,b2c,b2c};
    const float4_t c2init = {b3c,b3c,b3c,b3c};

    half8_t b1h[4];
    #pragma unroll
    for (int g=0;g<4;++g) {
        #pragma unroll
        for (int e=0;e<8;++e) b1h[g][e] = (_Float16)b1[8*g+e];
    }

    const float step = 2.0f/(float)(RR-1);
    float x = fmaf((float)i,  step, -1.0f);
    float y = fmaf((float)j_, step, -1.0f);
    float z = fmaf((float)k_, step, -1.0f);

    float accA[16], accB[16], accM[16];
    #pragma unroll
    for (int q=0;q<16;++q) { accA[q]=0.f; accB[q]=0.f; accM[q]=0.f; }

    for (int v = 0; v < NVIEW; ++v) {
        const float* P = poses + v*16;
        float px = fmaf(P[0],x, fmaf(P[1],y, fmaf(P[2], z, P[3])));
        float py = fmaf(P[4],x, fmaf(P[5],y, fmaf(P[6], z, P[7])));
        float pz = fmaf(P[8],x, fmaf(P[9],y, fmaf(P[10],z, P[11])));
        float u  = px/pz;
        float w  = py/pz;

        float mk = (pz > 0.f && u >= 0.f && u <= (float)(IW-1)
                              && w >= 0.f && w <= (float)(IH-1)) ? 1.f : 0.f;

        float fx0 = floorf(u), fy0 = floorf(w);
        float tx = u - fx0, ty = w - fy0;
        bool bx0 = (fx0 >=  0.f) && (fx0 <= (float)(IW-1));
        bool bx1 = (fx0 >= -1.f) && (fx0 <= (float)(IW-2));
        bool by0 = (fy0 >=  0.f) && (fy0 <= (float)(IH-1));
        bool by1 = (fy0 >= -1.f) && (fy0 <= (float)(IH-2));
        int x0 = (int)fminf(fmaxf(fx0,      0.f), (float)(IW-1));
        int x1 = (int)fminf(fmaxf(fx0+1.f,  0.f), (float)(IW-1));
        int y0 = (int)fminf(fmaxf(fy0,      0.f), (float)(IH-1));
        int y1 = (int)fminf(fmaxf(fy0+1.f,  0.f), (float)(IH-1));

        float w00 = (bx0&&by0) ? (1.f-tx)*(1.f-ty) : 0.f;
        float w10 = (bx1&&by0) ? tx*(1.f-ty)       : 0.f;
        float w01 = (bx0&&by1) ? (1.f-tx)*ty       : 0.f;
        float w11 = (bx1&&by1) ? tx*ty             : 0.f;

        _Float16 w00h = (_Float16)w00, w10h = (_Float16)w10;
        _Float16 w01h = (_Float16)w01, w11h = (_Float16)w11;

        const _Float16* gv = G + (size_t)v*VIEW_H;
        int o00 = (y0*IW + x0)*8;
        int o10 = (y0*IW + x1)*8;
        int o01 = (y1*IW + x0)*8;
        int o11 = (y1*IW + x1)*8;

        // packed f16 blend -> h1 row (4 x b128 writes)
        _Float16* rowp = &h1buf[wid][lane*40];
        #pragma unroll
        for (int g=0;g<4;++g) {
            const _Float16* pl = gv + (size_t)g*PLANE_H;
            half8_t a = *(const half8_t*)(pl + o00);
            half8_t b = *(const half8_t*)(pl + o10);
            half8_t c = *(const half8_t*)(pl + o01);
            half8_t d = *(const half8_t*)(pl + o11);
            half8_t r = a*w00h + b*w10h + c*w01h + d*w11h + b1h[g];
            r = __builtin_elementwise_max(r, (half8_t)(_Float16)0.f);
            ((half8_t*)rowp)[g] = r;
        }
        mkbuf[wid][lane] = mk;
        __builtin_amdgcn_wave_barrier();

        // 4 batches of 16 local voxel-rows through the 2-layer MFMA MLP
        #pragma unroll
        for (int b=0;b<4;++b) {
            half8_t a1 = *(const half8_t*)&h1buf[wid][(16*b+lc)*40 + lq*8];
            float4_t d1 = __builtin_amdgcn_mfma_f32_16x16x32_f16(a1, w2f, c1init, 0,0,0);
            #pragma unroll
            for (int r=0;r<4;++r)
                h2t[wid][(4*lq+r)*H2T_STRIDE + lc] = (_Float16)fmaxf(d1[r], 0.f);
            __builtin_amdgcn_wave_barrier();
            half4_t a2 = *(const half4_t*)&h2t[wid][lc*H2T_STRIDE + lq*4];
            float4_t d2 = __builtin_amdgcn_mfma_f32_16x16x16f16(a2, w3f, c2init, 0,0,0);
            float4 mkv = *(const float4*)&mkbuf[wid][16*b + lq*4];
            #pragma unroll
            for (int r=0;r<4;++r) {
                float h3 = d2[r];
                float m  = (r==0)?mkv.x:(r==1)?mkv.y:(r==2)?mkv.z:mkv.w;
                int idx = 4*b + r;
                accA[idx] = fmaf(m, h3,    accA[idx]);
                accB[idx] = fmaf(m, h3*h3, accB[idx]);
                accM[idx] += m;
            }
            __builtin_amdgcn_wave_barrier();
        }
        __builtin_amdgcn_wave_barrier();
    }

    // finalize: mean/var -> LDS transpose -> store (16-lane contiguous runs)
    float* fb = (float*)&h1buf[wid][0];   // 64 rows x 17 f32
    if (lc < 8) {
        #pragma unroll
        for (int b=0;b<4;++b) {
            #pragma unroll
            for (int r=0;r<4;++r) {
                int idx  = 4*b + r;
                int voxr = 16*b + 4*lq + r;
                float S   = accM[idx] + 1e-8f;
                float inv = 1.f/S;
                float sw  = accM[idx]*inv;
                float mean= accA[idx]*inv;
                float var = fmaf(-mean*mean, (2.f - sw), accB[idx]*inv);
                fb[voxr*17 + lc]     = mean;
                fb[voxr*17 + 8 + lc] = var;
            }
        }
    }
    __builtin_amdgcn_wave_barrier();
    #pragma unroll
    for (int c=0;c<16;++c)
        out[(size_t)c*NVOX + vox] = fb[lane*17 + c];
}

extern "C" void kernel_launch(void* const* d_in, const int* in_sizes, int n_in,
                              void* d_out, int out_size, void* d_ws, size_t ws_size,
                              hipStream_t stream)
{
    const float* feats = (const float*)d_in[0];
    const float* poses = (const float*)d_in[1];
    const float* W1    = (const float*)d_in[2];
    const float* b1    = (const float*)d_in[3];
    const float* W2    = (const float*)d_in[4];
    const float* b2    = (const float*)d_in[5];
    const float* W3    = (const float*)d_in[6];
    const float* b3    = (const float*)d_in[7];
    float* out = (float*)d_out;

    _Float16* G = (_Float16*)d_ws;   // 1 MB
    g_precompute<<<256, 256, 0, stream>>>(feats, W1, G);
    dgfv_main<<<5*5*RR, 256, 0, stream>>>(G, poses, b1, W2, b2, W3, b3, out);
}

// Round 8
// 110.688 us; speedup vs baseline: 1.0047x; 1.0047x over previous
//
#include <hip/hip_runtime.h>
#include <cstddef>

#define RR 80
#define NVIEW 4
#define CH 32
#define IH 64
#define IW 64
#define NPIX (IH*IW)
#define NVOX (RR*RR*RR)   // 512000

// G (f16) layout: [v][grp(4 x 8ch)][y][x][8 f16 = 16B]
#define PLANE_H (NPIX*8)
#define VIEW_H  (4*PLANE_H)

typedef _Float16 half4_t  __attribute__((ext_vector_type(4)));
typedef _Float16 half8_t  __attribute__((ext_vector_type(8)));
typedef float    float4_t __attribute__((ext_vector_type(4)));

// ---------------------------------------------------------------------------
// G[v][g][y][x][e] = sum_ic feats[v][ic][y][x] * W1[ic][8*g+e]  (f16 output)
// ---------------------------------------------------------------------------
__global__ __launch_bounds__(256) void g_precompute(
    const float* __restrict__ feats, const float* __restrict__ W1,
    _Float16* __restrict__ G)
{
    int g = blockIdx.x >> 6;                        // 0..3 (8-ch group)
    int p = (blockIdx.x & 63)*256 + threadIdx.x;    // pixel 0..16383
    __shared__ float sW1[CH*8];
    if (threadIdx.x < CH*8) {
        int ic = threadIdx.x >> 3, e = threadIdx.x & 7;
        sW1[threadIdx.x] = W1[ic*CH + 8*g + e];
    }
    __syncthreads();
    int v  = p >> 12;
    int yx = p & 4095;
    const float* fb = feats + ((size_t)v*CH)*NPIX + yx;
    float acc[8];
    #pragma unroll
    for (int e=0;e<8;++e) acc[e] = 0.f;
    #pragma unroll
    for (int ic=0; ic<CH; ++ic) {
        float fv = fb[(size_t)ic*NPIX];
        #pragma unroll
        for (int e=0;e<8;++e) acc[e] = fmaf(fv, sW1[ic*8+e], acc[e]);
    }
    half8_t h;
    #pragma unroll
    for (int e=0;e<8;++e) h[e] = (_Float16)acc[e];
    *(half8_t*)(G + (size_t)v*VIEW_H + (size_t)g*PLANE_H + (size_t)yx*8) = h;
}

// ---------------------------------------------------------------------------
// Main: zero-LDS MLP.  Transposed MFMA chain:
//   D1[f2][vox] = W2^T (A-frag) x H1^T (B-frag, built in-register by blend)
//   relu(D1) in C-layout IS the B-frag for 16x16x16  ->  feeds mfma2 directly
//   D2[fo'][vox] = W3^Tdup (A-frag) x relu(D1);  rows 8..15 duplicate 0..7 so
//   quads 0,1 hold h3 for mean and quads 2,3 an identical copy for var.
// Wave covers 64 consecutive voxels as 4 passes x 16 (vox = lane&15).
// ---------------------------------------------------------------------------
__global__ __launch_bounds__(256) void dgfv_main(
    const _Float16* __restrict__ G,   // [NVIEW][4][IH][IW][8]
    const float* __restrict__ poses,
    const float* __restrict__ b1,
    const float* __restrict__ W2, const float* __restrict__ b2,
    const float* __restrict__ W3, const float* __restrict__ b3,
    float* __restrict__ out)
{
    const int wid  = threadIdx.x >> 6;
    const int lane = threadIdx.x & 63;
    const int lq   = lane >> 4;
    const int lc   = lane & 15;
    const int vbase = blockIdx.x*256 + wid*64 + lc;  // voxel of pass p: vbase+16p

    // ---- wave-resident fragments ----
    half8_t w2a;   // A-frag of W2^T (byte-identical to B-frag of W2)
    #pragma unroll
    for (int j=0;j<8;++j) w2a[j] = (_Float16)W2[(lq*8+j)*16 + lc];
    half4_t w3a;   // A-frag of W3^T with rows 8..15 duplicating 0..7
    #pragma unroll
    for (int j=0;j<4;++j) w3a[j] = (_Float16)W3[(lq*4+j)*8 + (lc&7)];
    float4_t c1init, c2init;
    #pragma unroll
    for (int r=0;r<4;++r) {
        c1init[r] = b2[lq*4+r];
        c2init[r] = b3[(lq*4+r)&7];
    }
    half8_t b1h;   // bias for channel group lq
    #pragma unroll
    for (int j=0;j<8;++j) b1h[j] = (_Float16)b1[8*lq+j];

    // ---- per-pass voxel coords ----
    const float step = 2.0f/(float)(RR-1);
    float xs[4], ys[4], zs[4];
    #pragma unroll
    for (int p=0;p<4;++p) {
        int vx = vbase + 16*p;
        int i  = vx % RR;
        int t  = vx / RR;
        int j_ = t % RR;
        int k_ = t / RR;
        xs[p] = fmaf((float)i,  step, -1.0f);
        ys[p] = fmaf((float)j_, step, -1.0f);
        zs[p] = fmaf((float)k_, step, -1.0f);
    }

    float accA[16], accB[16], accM[4];
    #pragma unroll
    for (int q=0;q<16;++q) { accA[q]=0.f; accB[q]=0.f; }
    #pragma unroll
    for (int p=0;p<4;++p) accM[p]=0.f;

    for (int v = 0; v < NVIEW; ++v) {
        const float* P = poses + v*16;               // uniform -> scalar
        const _Float16* pl = G + (size_t)v*VIEW_H + (size_t)lq*PLANE_H;

        #pragma unroll
        for (int p=0;p<4;++p) {
            float x = xs[p], y = ys[p], z = zs[p];
            float px = fmaf(P[0],x, fmaf(P[1],y, fmaf(P[2], z, P[3])));
            float py = fmaf(P[4],x, fmaf(P[5],y, fmaf(P[6], z, P[7])));
            float pz = fmaf(P[8],x, fmaf(P[9],y, fmaf(P[10],z, P[11])));
            float r0 = __builtin_amdgcn_rcpf(pz);
            r0 = r0*(2.0f - pz*r0);                  // 1 Newton step
            float u  = px*r0;
            float w  = py*r0;

            float mk = (pz > 0.f && u >= 0.f && u <= (float)(IW-1)
                                  && w >= 0.f && w <= (float)(IH-1)) ? 1.f : 0.f;

            float fx0 = floorf(u), fy0 = floorf(w);
            float tx = u - fx0, ty = w - fy0;
            bool bx0 = (fx0 >=  0.f) && (fx0 <= (float)(IW-1));
            bool bx1 = (fx0 >= -1.f) && (fx0 <= (float)(IW-2));
            bool by0 = (fy0 >=  0.f) && (fy0 <= (float)(IH-1));
            bool by1 = (fy0 >= -1.f) && (fy0 <= (float)(IH-2));
            int x0 = (int)fminf(fmaxf(fx0,      0.f), (float)(IW-1));
            int x1 = (int)fminf(fmaxf(fx0+1.f,  0.f), (float)(IW-1));
            int y0 = (int)fminf(fmaxf(fy0,      0.f), (float)(IH-1));
            int y1 = (int)fminf(fmaxf(fy0+1.f,  0.f), (float)(IH-1));

            float w00 = (bx0&&by0) ? (1.f-tx)*(1.f-ty) : 0.f;
            float w10 = (bx1&&by0) ? tx*(1.f-ty)       : 0.f;
            float w01 = (bx0&&by1) ? (1.f-tx)*ty       : 0.f;
            float w11 = (bx1&&by1) ? tx*ty             : 0.f;

            _Float16 w00h = (_Float16)w00, w10h = (_Float16)w10;
            _Float16 w01h = (_Float16)w01, w11h = (_Float16)w11;

            // 4 corner gathers for (voxel lc, channel group lq)
            half8_t a = *(const half8_t*)(pl + (y0*IW + x0)*8);
            half8_t b = *(const half8_t*)(pl + (y0*IW + x1)*8);
            half8_t c = *(const half8_t*)(pl + (y1*IW + x0)*8);
            half8_t d = *(const half8_t*)(pl + (y1*IW + x1)*8);
            half8_t h1 = a*w00h + b*w10h + c*w01h + d*w11h + b1h;
            h1 = __builtin_elementwise_max(h1, (half8_t)(_Float16)0.f);

            // layer 2: D1[f2][vox]  (A = W2^T, B = H1^T built in-register)
            float4_t d1 = __builtin_amdgcn_mfma_f32_16x16x32_f16(w2a, h1, c1init, 0,0,0);
            half4_t h2;
            #pragma unroll
            for (int r=0;r<4;++r) h2[r] = (_Float16)fmaxf(d1[r], 0.f);

            // layer 3: D2[fo'][vox]  (relu(D1) is already a valid B-frag)
            float4_t d2 = __builtin_amdgcn_mfma_f32_16x16x16f16(w3a, h2, c2init, 0,0,0);

            #pragma unroll
            for (int r=0;r<4;++r) {
                float h3 = d2[r];
                float t  = mk*h3;
                accA[4*p+r] += t;
                accB[4*p+r] = fmaf(t, h3, accB[4*p+r]);
            }
            accM[p] += mk;
        }
    }

    // epilogue: quads 0,1 -> mean (c=4lq+r), quads 2,3 -> var (c=4lq+r)
    #pragma unroll
    for (int p=0;p<4;++p) {
        float S   = accM[p] + 1e-8f;
        float inv = 1.f/S;
        float sw  = accM[p]*inv;
        #pragma unroll
        for (int r=0;r<4;++r) {
            float mean = accA[4*p+r]*inv;
            float var  = fmaf(-mean*mean, (2.f - sw), accB[4*p+r]*inv);
            float val  = (lq < 2) ? mean : var;
            int   cch  = 4*lq + r;
            out[(size_t)cch*NVOX + vbase + 16*p] = val;
        }
    }
}

extern "C" void kernel_launch(void* const* d_in, const int* in_sizes, int n_in,
                              void* d_out, int out_size, void* d_ws, size_t ws_size,
                              hipStream_t stream)
{
    const float* feats = (const float*)d_in[0];
    const float* poses = (const float*)d_in[1];
    const float* W1    = (const float*)d_in[2];
    const float* b1    = (const float*)d_in[3];
    const float* W2    = (const float*)d_in[4];
    const float* b2    = (const float*)d_in[5];
    const float* W3    = (const float*)d_in[6];
    const float* b3    = (const float*)d_in[7];
    float* out = (float*)d_out;

    _Float16* G = (_Float16*)d_ws;   // 1 MB
    g_precompute<<<256, 256, 0, stream>>>(feats, W1, G);
    dgfv_main<<<NVOX/256, 256, 0, stream>>>(G, poses, b1, W2, b2, W3, b3, out);
}

// Round 9
// 103.122 us; speedup vs baseline: 1.0784x; 1.0734x over previous
//
#include <hip/hip_runtime.h>
#include <cstddef>

#define RR 80
#define NVIEW 4
#define CH 32
#define IH 64
#define IW 64
#define NPIX (IH*IW)
#define NVOX (RR*RR*RR)   // 512000

// G (f16) layout: [v][grp(4 x 8ch)][y][x][8 f16 = 16B]
#define PLANE_H (NPIX*8)
#define VIEW_H  (4*PLANE_H)

typedef _Float16 half4_t  __attribute__((ext_vector_type(4)));
typedef _Float16 half8_t  __attribute__((ext_vector_type(8)));
typedef float    float4_t __attribute__((ext_vector_type(4)));

// ---------------------------------------------------------------------------
// G[v][g][y][x][e] = sum_ic feats[v][ic][y][x] * W1[ic][8*g+e]  (f16 output)
// ---------------------------------------------------------------------------
__global__ __launch_bounds__(256) void g_precompute(
    const float* __restrict__ feats, const float* __restrict__ W1,
    _Float16* __restrict__ G)
{
    int g = blockIdx.x >> 6;                        // 0..3 (8-ch group)
    int p = (blockIdx.x & 63)*256 + threadIdx.x;    // pixel 0..16383
    __shared__ float sW1[CH*8];
    if (threadIdx.x < CH*8) {
        int ic = threadIdx.x >> 3, e = threadIdx.x & 7;
        sW1[threadIdx.x] = W1[ic*CH + 8*g + e];
    }
    __syncthreads();
    int v  = p >> 12;
    int yx = p & 4095;
    const float* fb = feats + ((size_t)v*CH)*NPIX + yx;
    float acc[8];
    #pragma unroll
    for (int e=0;e<8;++e) acc[e] = 0.f;
    #pragma unroll
    for (int ic=0; ic<CH; ++ic) {
        float fv = fb[(size_t)ic*NPIX];
        #pragma unroll
        for (int e=0;e<8;++e) acc[e] = fmaf(fv, sW1[ic*8+e], acc[e]);
    }
    half8_t h;
    #pragma unroll
    for (int e=0;e<8;++e) h[e] = (_Float16)acc[e];
    *(half8_t*)(G + (size_t)v*VIEW_H + (size_t)g*PLANE_H + (size_t)yx*8) = h;
}

// ---------------------------------------------------------------------------
// Main: zero-LDS transposed MFMA MLP; pass-outer loop (small live set);
// clamp-based bounds (no per-corner tests — OOB contributions carry weight 0
// and x1/y1 overreads stay inside ws with zero weight / mk=0).
// ---------------------------------------------------------------------------
__global__ __launch_bounds__(256) void dgfv_main(
    const _Float16* __restrict__ G,   // [NVIEW][4][IH][IW][8]
    const float* __restrict__ poses,
    const float* __restrict__ b1,
    const float* __restrict__ W2, const float* __restrict__ b2,
    const float* __restrict__ W3, const float* __restrict__ b3,
    float* __restrict__ out)
{
    const int wid  = threadIdx.x >> 6;
    const int lane = threadIdx.x & 63;
    const int lq   = lane >> 4;
    const int lc   = lane & 15;
    const int vbase = blockIdx.x*256 + wid*64 + lc;  // voxel of pass p: vbase+16p

    // ---- wave-resident fragments ----
    half8_t w2a;   // A-frag of W2^T: A[m=lc][k=lq*8+j] = W2[k][m]
    #pragma unroll
    for (int j=0;j<8;++j) w2a[j] = (_Float16)W2[(lq*8+j)*16 + lc];
    half4_t w3a;   // A-frag of W3^T, rows 8..15 duplicate 0..7
    #pragma unroll
    for (int j=0;j<4;++j) w3a[j] = (_Float16)W3[(lq*4+j)*8 + (lc&7)];
    float4_t c1init, c2init;
    #pragma unroll
    for (int r=0;r<4;++r) {
        c1init[r] = b2[lq*4+r];
        c2init[r] = b3[(lq*4+r)&7];
    }
    half8_t b1h;   // bias for channel group lq
    #pragma unroll
    for (int j=0;j<8;++j) b1h[j] = (_Float16)b1[8*lq+j];

    const float step = 2.0f/(float)(RR-1);

    #pragma unroll
    for (int p=0;p<4;++p) {
        int vx = vbase + 16*p;
        int i  = vx % RR;
        int t  = vx / RR;
        int j_ = t % RR;
        int k_ = t / RR;
        float x = fmaf((float)i,  step, -1.0f);
        float y = fmaf((float)j_, step, -1.0f);
        float z = fmaf((float)k_, step, -1.0f);

        float accA[4], accB[4], accM = 0.f;
        #pragma unroll
        for (int r=0;r<4;++r) { accA[r]=0.f; accB[r]=0.f; }

        #pragma unroll
        for (int v = 0; v < NVIEW; ++v) {
            const float* P = poses + v*16;           // uniform -> scalar
            float px = fmaf(P[0],x, fmaf(P[1],y, fmaf(P[2], z, P[3])));
            float py = fmaf(P[4],x, fmaf(P[5],y, fmaf(P[6], z, P[7])));
            float pz = fmaf(P[8],x, fmaf(P[9],y, fmaf(P[10],z, P[11])));
            float r0 = __builtin_amdgcn_rcpf(pz);
            r0 = r0*(2.0f - pz*r0);                  // 1 Newton step
            float u  = px*r0;
            float w  = py*r0;

            float mk = (pz > 0.f && u >= 0.f && u <= (float)(IW-1)
                                  && w >= 0.f && w <= (float)(IH-1)) ? 1.f : 0.f;

            // NaN-safe clamp; when mk==1 this is the identity
            float uc = fminf(fmaxf(u, 0.f), (float)(IW-1));
            float wc = fminf(fmaxf(w, 0.f), (float)(IH-1));
            float fx0 = floorf(uc), fy0 = floorf(wc);
            float tx = uc - fx0, ty = wc - fy0;
            int x0 = (int)fx0, y0 = (int)fy0;
            float wx0 = 1.f - tx, wy0 = 1.f - ty;

            _Float16 w00h = (_Float16)(wx0*wy0), w10h = (_Float16)(tx*wy0);
            _Float16 w01h = (_Float16)(wx0*ty),  w11h = (_Float16)(tx*ty);

            const _Float16* base = G + (size_t)v*VIEW_H + (size_t)lq*PLANE_H
                                     + (size_t)(y0*IW + x0)*8;
            half8_t a = *(const half8_t*)(base);
            half8_t b = *(const half8_t*)(base + 8);        // x1 (wt 0 if x0=63)
            half8_t c = *(const half8_t*)(base + IW*8);     // y1
            half8_t d = *(const half8_t*)(base + IW*8 + 8);
            half8_t h1 = a*w00h + b*w10h + c*w01h + d*w11h + b1h;
            h1 = __builtin_elementwise_max(h1, (half8_t)(_Float16)0.f);

            // layer 2: D1[f2][vox]  (A = W2^T, B = H1^T built in-register)
            float4_t d1 = __builtin_amdgcn_mfma_f32_16x16x32_f16(w2a, h1, c1init, 0,0,0);
            half4_t h2;
            #pragma unroll
            for (int r=0;r<4;++r) h2[r] = (_Float16)fmaxf(d1[r], 0.f);

            // layer 3: D2[fo'][vox]  (relu(D1) C-layout == B-frag for K=16)
            float4_t d2 = __builtin_amdgcn_mfma_f32_16x16x16f16(w3a, h2, c2init, 0,0,0);

            #pragma unroll
            for (int r=0;r<4;++r) {
                float h3 = d2[r];
                float tt = mk*h3;
                accA[r] += tt;
                accB[r]  = fmaf(tt, h3, accB[r]);
            }
            accM += mk;
        }

        // per-pass epilogue: quads 0,1 -> mean, quads 2,3 -> var
        float S   = accM + 1e-8f;
        float inv = 1.f/S;
        float sw  = accM*inv;
        #pragma unroll
        for (int r=0;r<4;++r) {
            float mean = accA[r]*inv;
            float var  = fmaf(-mean*mean, (2.f - sw), accB[r]*inv);
            float val  = (lq < 2) ? mean : var;
            int   cch  = 4*lq + r;
            out[(size_t)cch*NVOX + vx] = val;
        }
    }
}

extern "C" void kernel_launch(void* const* d_in, const int* in_sizes, int n_in,
                              void* d_out, int out_size, void* d_ws, size_t ws_size,
                              hipStream_t stream)
{
    const float* feats = (const float*)d_in[0];
    const float* poses = (const float*)d_in[1];
    const float* W1    = (const float*)d_in[2];
    const float* b1    = (const float*)d_in[3];
    const float* W2    = (const float*)d_in[4];
    const float* b2    = (const float*)d_in[5];
    const float* W3    = (const float*)d_in[6];
    const float* b3    = (const float*)d_in[7];
    float* out = (float*)d_out;

    _Float16* G = (_Float16*)d_ws;   // 1 MB
    g_precompute<<<256, 256, 0, stream>>>(feats, W1, G);
    dgfv_main<<<NVOX/256, 256, 0, stream>>>(G, poses, b1, W2, b2, W3, b3, out);
}